// Round 6
// baseline (2277.863 us; speedup 1.0000x reference)
//
#include <hip/hip_runtime.h>

// SDGCN32: 31-layer GCN, N=100k, E=3.2M, F=32.
//  - hs = dis*h carried FP32, row-major [n][32] (fp16 carrier fails 31-layer error amp)
//  - CSR per (dst, src-bucket), NB=4 (R7 optimum); padded to x4 per segment (R17),
//    pad slots -> sentinel row N kept all-zero in hs (exact no-op adds).
//  - R18/R19 (R19 = byte-identical resubmit of R18; R18 bench was an infra failure,
//    "container failed twice" — no device-side evidence against the kernel; OOB,
//    deadlock, and replay-safety audits all clean):
//    (1) k_cscatter/k_chist were 1 block/CU (9% occupancy, 63us) -> 2048 blocks.
//    (2) k_gcn: wave = 4 nodes x 2 halves x 8 quads (was 8 nodes x 8 quads). Each
//    node's padded segment is walked by TWO 8-lane groups (half h takes quads
//    rsQ+h, rsQ+h+2, ...), halving per-wave critical path and doubling wave count
//    (25k waves -> better slot fill + tail balance). Halves combined by shfl_xor(8);
//    epilogue duplicated across halves, stores gated h==0 (out += must not double).
//    Same vmem instruction count (each gather still serves 8 rows/edges).
//  - R17 bugfix retained: group-last nodes' bucket-3 end = gend[g] (padded group end),
//    NOT rp4[rbase+4] (next group's base across unused slack -> garbage reads).
//  - k_x0 (R15): 8 nodes/block; n0==x0 identity; transpose epilogue. (R14's 64-node
//    serial-group variant regressed: barriers killed TLP; do not revisit.)
//  - out accumulated online: out += mynorm(x_j)@Mn_j (+ raw x_j@Rw_j, j in {0,1,16})

#define NB 4        // src buckets
#define BSHIFT 15   // bucket = src >> 15 (32768 nodes = 4 MiB fp32 chunk)
#define CSH 9       // coarse bin = dst >> 9 (512 nodes)
#define GSLACK 6152 // per-group csr padding slack: 2048 bins * 3 + alignment

__device__ __forceinline__ float shflx(float v, int m) { return __shfl_xor(v, m, 64); }

// ---------- pass A1: coarse histogram ----------
__global__ __launch_bounds__(256) void k_chist(const int* __restrict__ dst, int E,
                                               int* __restrict__ gcnt, int G1) {
    __shared__ int lh[256];
    lh[threadIdx.x] = 0;
    __syncthreads();
    int chunk = (E + gridDim.x - 1) / gridDim.x;
    int s0 = blockIdx.x * chunk, s1 = min(E, s0 + chunk);
    for (int e = s0 + threadIdx.x; e < s1; e += 256)
        atomicAdd(&lh[dst[e] >> CSH], 1);
    __syncthreads();
    if (threadIdx.x < G1 && lh[threadIdx.x])
        atomicAdd(&gcnt[threadIdx.x], lh[threadIdx.x]);
}

// ---------- pass A2: scan coarse bins (G1 <= 256) ----------
__global__ void k_cscan(const int* __restrict__ gcnt, int* __restrict__ gptr,
                        int* __restrict__ gcur, int G1, int E) {
    __shared__ int s[256];
    int t = threadIdx.x;
    int v = (t < G1) ? gcnt[t] : 0;
    s[t] = v;
    __syncthreads();
    for (int off = 1; off < 256; off <<= 1) {
        int tv = (t >= off) ? s[t - off] : 0;
        __syncthreads();
        s[t] += tv;
        __syncthreads();
    }
    if (t < G1) { int ex = s[t] - v; gptr[t] = ex; gcur[t] = ex; }
    if (t == 0) gptr[G1] = E;
}

// ---------- pass A3: reservation scatter of packed (src | ldst<<17) ----------
__global__ __launch_bounds__(256) void k_cscatter(const int* __restrict__ src,
                                                  const int* __restrict__ dst, int E,
                                                  int* __restrict__ gcur,
                                                  int* __restrict__ tmp, int G1) {
    __shared__ int lh[256], lc[256];
    lh[threadIdx.x] = 0;
    __syncthreads();
    int chunk = (E + gridDim.x - 1) / gridDim.x;
    int s0 = blockIdx.x * chunk, s1 = min(E, s0 + chunk);
    for (int e = s0 + threadIdx.x; e < s1; e += 256)
        atomicAdd(&lh[dst[e] >> CSH], 1);
    __syncthreads();
    if (threadIdx.x < G1) {
        int c = lh[threadIdx.x];
        lc[threadIdx.x] = c ? atomicAdd(&gcur[threadIdx.x], c) : 0;
    }
    __syncthreads();
    for (int e = s0 + threadIdx.x; e < s1; e += 256) {
        int d = dst[e];
        int pos = atomicAdd(&lc[d >> CSH], 1);
        tmp[pos] = src[e] | ((d & ((1 << CSH) - 1)) << 17);
    }
}

// ---------- pass B: per coarse group -> PADDED fine CSR (rp4, csr, dis, gend) ----------
__global__ __launch_bounds__(256) void k_build(const int* __restrict__ tmp,
                                               const int* __restrict__ gptr,
                                               int* __restrict__ rp4,
                                               int* __restrict__ csr,
                                               float* __restrict__ dis,
                                               int* __restrict__ gend,
                                               int N, int M) {
    __shared__ int h[2048];     // fine bins: 512 nodes x NB
    __shared__ int c[2048];     // absolute scatter cursors
    __shared__ int s[256];
    int g = blockIdx.x;
    int gb = gptr[g], ge = gptr[g + 1];
    int gbP = ((gb + 3) & ~3) + g * GSLACK;
    int t = threadIdx.x;
#pragma unroll
    for (int k = 0; k < 8; ++k) h[t * 8 + k] = 0;
    __syncthreads();
    for (int e = gb + t; e < ge; e += 256) {
        int w = tmp[e];
        int srcv = w & 0x1FFFF, ldst = w >> 17;
        atomicAdd(&h[ldst * NB + (srcv >> BSHIFT)], 1);
    }
    __syncthreads();
    int base8 = t * 8;
    int loc[8], sumP = 0;
#pragma unroll
    for (int k = 0; k < 8; ++k) { loc[k] = h[base8 + k]; sumP += (loc[k] + 3) & ~3; }
    s[t] = sumP;
    __syncthreads();
    for (int off = 1; off < 256; off <<= 1) {
        int tv = (t >= off) ? s[t - off] : 0;
        __syncthreads();
        s[t] += tv;
        __syncthreads();
    }
    int runP = s[t] - sumP;
    int rowbase = g * 2048;
#pragma unroll
    for (int k = 0; k < 8; ++k) {
        int i = base8 + k;
        int abs0 = gbP + runP;
        c[i] = abs0;
        int ig = rowbase + i;
        if (ig <= M) rp4[ig] = abs0;
        int lp = (loc[k] + 3) & ~3;
        for (int j = loc[k]; j < lp; ++j) csr[abs0 + j] = N;   // sentinel pads
        runP += lp;
    }
    __syncthreads();
    for (int e = gb + t; e < ge; e += 256) {
        int w = tmp[e];
        int srcv = w & 0x1FFFF, ldst = w >> 17;
        int pos = atomicAdd(&c[ldst * NB + (srcv >> BSHIFT)], 1);
        csr[pos] = srcv;
    }
    // degrees -> dis (actual counts, not padded)
    int nodebase = g << CSH;
    for (int ln = t; ln < (1 << CSH); ln += 256) {
        int n = nodebase + ln;
        if (n < N) {
            int d = h[ln * NB] + h[ln * NB + 1] + h[ln * NB + 2] + h[ln * NB + 3];
            dis[n] = rsqrtf((float)d + 1.0f);
        }
    }
    if (t == 0) gend[g] = gbP + s[255];                        // true padded end
    if (g == gridDim.x - 1 && t == 0) rp4[M] = gbP + s[255];   // padded end marker
}

// ---------- coefficients, layout [j][o][c]; C0 = Mn[j=0] + Rw[j=0] (n0==x0 identity) ----------
__global__ void k_mnorm(const float* __restrict__ W2, float* __restrict__ Mn,
                        float* __restrict__ Rw, float* __restrict__ C0) {
    int idx = blockIdx.x * blockDim.x + threadIdx.x;
    if (idx >= 32 * 32 * 10) return;
    int c = idx % 32, o = (idx / 32) % 10, j = idx / 320;
    float v = 0.f;
    if (j >= 2 && j != 16) v += W2[(32 * j + c) * 10 + o];
    if (j <= 29 && j != 14) v -= W2[(32 * (j + 2) + c) * 10 + o];
    Mn[idx] = v;
    float rw = (j == 0 || j == 1 || j == 16) ? W2[(32 * j + c) * 10 + o] : 0.f;
    Rw[idx] = rw;
    if (j == 0) C0[idx] = v + rw;    // idx = o*32+c for j==0
}

// ---------- layer 0 (R15): R13 structure + transpose epilogue ----------
__global__ __launch_bounds__(256) void k_x0(
    const float* __restrict__ x, const float* __restrict__ W1, const float* __restrict__ b1,
    const float* __restrict__ b2, const float* __restrict__ C0,
    const float* __restrict__ dis, float* __restrict__ hs, float* __restrict__ out, int N)
{
    __shared__ float Wt[32 * 68];      // W1 transposed [c][k], pad 68 (bank spread)
    __shared__ float xs[8 * 64];       // 8 staged x rows
    __shared__ float bs[32];
    __shared__ float Cs[10 * 36];      // combined j=0 coeffs [o][c], pad 36
    __shared__ float xmat[8 * 36];     // x0 transposed [node][c], pad 36
    int t = threadIdx.x;
    for (int i = t; i < 2048; i += 256) {
        int k = i >> 5, cc = i & 31;
        Wt[cc * 68 + k] = W1[i];
    }
    for (int i = t; i < 320; i += 256) {
        int o = i >> 5, cc = i & 31;
        Cs[o * 36 + cc] = C0[i];
    }
    if (t < 32) bs[t] = b1[t];
    // maintain all-zero sentinel row N of hs (gathered by padded csr slots)
    if (blockIdx.x == 0 && t < 32) hs[(size_t)N * 32 + t] = 0.f;
    int base = blockIdx.x * 8;
    {
        int nf2 = (min(N - base, 8)) * 32;               // float2 count
        const float2* x2 = (const float2*)(x + (size_t)base * 64);
        float2* xs2 = (float2*)xs;
        for (int i = t; i < nf2; i += 256) xs2[i] = x2[i];
    }
    __syncthreads();

    int node8 = t >> 5, c = t & 31;
    int n = base + node8;
    bool nvalid = (n < N);

    // 64-dot: xs broadcast (same addr per half) + Wt float4 (4-way conflict, 1.58x)
    const float4* xs4 = (const float4*)(xs + node8 * 64);
    const float4* Wt4 = (const float4*)(Wt + c * 68);
    float acc = bs[c];
#pragma unroll
    for (int k4 = 0; k4 < 16; ++k4) {
        float4 xv = xs4[k4];
        float4 wv = Wt4[k4];
        acc += xv.x * wv.x + xv.y * wv.y + xv.z * wv.z + xv.w * wv.w;
    }
    acc = fmaxf(acc, 0.f);

    // mynorm over this node's 32 channels (butterfly stays within 32-lane half)
    float mn = acc, mx = acc;
#pragma unroll
    for (int m = 1; m <= 16; m <<= 1) { mn = fminf(mn, shflx(mn, m)); mx = fmaxf(mx, shflx(mx, m)); }
    float x0 = 2.f * (acc - mn) / (mx - mn + 1e-8f) - 1.f;
    if (nvalid) {
        float dn = dis[n];
        hs[(size_t)n * 32 + c] = dn * x0;                // 2x128B coalesced per wave
        xmat[node8 * 36 + c] = x0;                       // conflict-free (stride 36)
    }
    // n0 = mynorm(x0) == x0 to ~1e-8 (x0 already spans [-1,1]); butterfly #2 deleted.
    __syncthreads();

    // out init via transpose: 80 threads, one (node,o) each; 8x float4 LDS dot.
    if (t < 80) {
        int n8 = t / 10, o = t - n8 * 10;
        int no = base + n8;
        if (no < N) {
            const float4* xr = (const float4*)(xmat + n8 * 36);
            const float4* cr = (const float4*)(Cs + o * 36);
            float a = 0.f;
#pragma unroll
            for (int k = 0; k < 8; ++k) {
                float4 xv = xr[k];
                float4 cv = cr[k];
                a += xv.x * cv.x + xv.y * cv.y + xv.z * cv.z + xv.w * cv.w;
            }
            out[(size_t)no * 10 + o] = b2[o] + a;        // 320B contiguous per block
        }
    }
}

// ---------- GCN layer (R18): 4 nodes x 2 halves x 8 quads per wave ----------
__global__ __launch_bounds__(256) void k_gcn(
    const float4* __restrict__ hs_in, float4* __restrict__ hs_out,
    const float* __restrict__ dis, const int* __restrict__ rp4,
    const int* __restrict__ csr, const int* __restrict__ gend,
    const float* __restrict__ W, const float* __restrict__ b,
    const float* __restrict__ Mn, const float* __restrict__ Rw,
    float* __restrict__ out, int N, int israw)
{
    __shared__ float Ws[1024];   // W [k][c]
    __shared__ float bs[32];
    __shared__ float Ms[320];    // Mn_j [o][c]
    __shared__ float Rs[320];    // Rw_j [o][c]
    for (int i = threadIdx.x; i < 1024; i += 256) Ws[i] = W[i];
    for (int i = threadIdx.x; i < 320; i += 256) { Ms[i] = Mn[i]; Rs[i] = Rw[i]; }
    if (threadIdx.x < 32) bs[threadIdx.x] = b[threadIdx.x];
    // keep sentinel row N of hs_out all-zero for the NEXT layer's gathers
    if (blockIdx.x == 0 && threadIdx.x < 8)
        hs_out[(size_t)N * 8 + threadIdx.x] = make_float4(0.f, 0.f, 0.f, 0.f);
    __syncthreads();

    int lane = threadIdx.x & 63;
    int q = lane & 7;            // channel quad c = 4q..4q+3
    int h = (lane >> 3) & 1;     // segment half (even/odd quads)
    int i4 = lane >> 4;          // node-sub 0..3 (within wave)
    int wave = threadIdx.x >> 6;
    int n = blockIdx.x * 16 + wave * 4 + i4;
    bool valid = (n < N);
    int nn = valid ? n : (N - 1);       // clamp: extra harmless loads only

    // self-loop term on half 0 only (halves are summed at the end)
    float4 acc = (h == 0) ? hs_in[(size_t)nn * 8 + q]
                          : make_float4(0.f, 0.f, 0.f, 0.f);

    int rbase = nn * NB;
    // bucket-3 terminator: group-last nodes must use the group's true padded end
    int e3 = ((nn & ((1 << CSH) - 1)) == ((1 << CSH) - 1)) ? gend[nn >> CSH]
                                                          : rp4[rbase + 4];
    const int4* csr4 = (const int4*)csr;
    int qd = (rp4[rbase] >> 2) + h;      // this half's first quad (stride 2 quads)
    int4 idx = csr4[qd];                 // prefetch (segments 16B-aligned, padded x4)
    for (int p = 0; p < NB; ++p) {
        int reQ = ((p == NB - 1) ? e3 : rp4[rbase + p + 1]) >> 2;
        for (; qd < reQ; qd += 2) {
            int s0 = idx.x, s1 = idx.y, s2 = idx.z, s3 = idx.w;
            idx = csr4[qd + 2];          // prefetch next (tail overrun lands in slack)
            float4 v0 = hs_in[(size_t)(s0 * 8 + q)];
            float4 v1 = hs_in[(size_t)(s1 * 8 + q)];
            float4 v2 = hs_in[(size_t)(s2 * 8 + q)];
            float4 v3 = hs_in[(size_t)(s3 * 8 + q)];
            acc.x += v0.x; acc.y += v0.y; acc.z += v0.z; acc.w += v0.w;
            acc.x += v1.x; acc.y += v1.y; acc.z += v1.z; acc.w += v1.w;
            acc.x += v2.x; acc.y += v2.y; acc.z += v2.z; acc.w += v2.w;
            acc.x += v3.x; acc.y += v3.y; acc.z += v3.z; acc.w += v3.w;
        }
        qd = reQ + h;                    // next bucket's start for this half
        if (p < NB - 1) idx = csr4[qd];  // re-prefetch; latency hidden by barrier
        __syncthreads();     // bucket phase alignment (uniform: all threads loop NB times)
    }

    // combine the two half-segment partials (all lanes end with the full sum)
    acc.x += shflx(acc.x, 8); acc.y += shflx(acc.y, 8);
    acc.z += shflx(acc.z, 8); acc.w += shflx(acc.w, 8);

    float dn = dis[nn];
    float4 g = make_float4(dn * acc.x, dn * acc.y, dn * acc.z, dn * acc.w);

    // GEMM: xn[quad q of node i] = b + sum_k g_i[k] * W[k][4q..4q+3]
    // (lane&0x38 = own 8-lane group base; both halves compute duplicates)
    const float4* W4 = (const float4*)Ws;
    float4 bb = ((const float4*)bs)[q];
    float4 xn = bb;
    int ibase = lane & 0x38;
#pragma unroll
    for (int kp = 0; kp < 8; ++kp) {
        int sl = ibase | kp;     // lane holding quad kp of this node (same half)
        float gx = __shfl(g.x, sl, 64);
        float gy = __shfl(g.y, sl, 64);
        float gz = __shfl(g.z, sl, 64);
        float gw = __shfl(g.w, sl, 64);
        float4 w0 = W4[(kp * 4 + 0) * 8 + q];
        float4 w1 = W4[(kp * 4 + 1) * 8 + q];
        float4 w2 = W4[(kp * 4 + 2) * 8 + q];
        float4 w3 = W4[(kp * 4 + 3) * 8 + q];
        xn.x += gx * w0.x + gy * w1.x + gz * w2.x + gw * w3.x;
        xn.y += gx * w0.y + gy * w1.y + gz * w2.y + gw * w3.y;
        xn.z += gx * w0.z + gy * w1.z + gz * w2.z + gw * w3.z;
        xn.w += gx * w0.w + gy * w1.w + gz * w2.w + gw * w3.w;
    }

    if (valid && h == 0)
        hs_out[(size_t)n * 8 + q] = make_float4(dn * xn.x, dn * xn.y, dn * xn.z, dn * xn.w);

    // mynorm over node's 32 channels: local 4, then butterfly over q bits (1,2,4)
    float mn = fminf(fminf(xn.x, xn.y), fminf(xn.z, xn.w));
    float mx = fmaxf(fmaxf(xn.x, xn.y), fmaxf(xn.z, xn.w));
#pragma unroll
    for (int m = 1; m <= 4; m <<= 1) { mn = fminf(mn, shflx(mn, m)); mx = fmaxf(mx, shflx(mx, m)); }
    float sc = 2.f / (mx - mn + 1e-8f);
    float4 nr = make_float4((xn.x - mn) * sc - 1.f, (xn.y - mn) * sc - 1.f,
                            (xn.z - mn) * sc - 1.f, (xn.w - mn) * sc - 1.f);

    // out accum: t[o] = nr . Mn[o][:] (+ xn . Rw[o][:]); butterfly within q bits
    const float4* M4 = (const float4*)Ms;
    const float4* R4 = (const float4*)Rs;
    float outA = 0.f, outB = 0.f;
#pragma unroll
    for (int o = 0; o < 10; ++o) {
        float4 m4 = M4[o * 8 + q];
        float t = nr.x * m4.x + nr.y * m4.y + nr.z * m4.z + nr.w * m4.w;
        if (israw) {
            float4 r4 = R4[o * 8 + q];
            t += xn.x * r4.x + xn.y * r4.y + xn.z * r4.z + xn.w * r4.w;
        }
        t += shflx(t, 1); t += shflx(t, 2); t += shflx(t, 4);
        if (o == q) outA = t;
        if (o == 8 + q) outB = t;
    }
    if (valid && h == 0) {       // h gate: out += must fire exactly once per (n,o)
        out[n * 10 + q] += outA;
        if (q < 2) out[n * 10 + 8 + q] += outB;
    }
}

extern "C" void kernel_launch(void* const* d_in, const int* in_sizes, int n_in,
                              void* d_out, int out_size, void* d_ws, size_t ws_size,
                              hipStream_t stream)
{
    const float* x  = (const float*)d_in[0];
    const int*   ei = (const int*)d_in[1];
    const float* W1 = (const float*)d_in[2];
    const float* b1 = (const float*)d_in[3];
    const float* Wc = (const float*)d_in[4];
    const float* bc = (const float*)d_in[5];
    const float* W2 = (const float*)d_in[6];
    const float* b2 = (const float*)d_in[7];
    float* out = (float*)d_out;

    const int N = in_sizes[0] / 64;
    const int E = in_sizes[1] / 2;
    const int M = N * NB;                     // (node,bucket) rows
    const int G1 = (N + (1 << CSH) - 1) >> CSH;   // 196 coarse bins (<=256)
    const int* src = ei;
    const int* dst = ei + E;

    char* ws = (char*)d_ws;
    size_t off = 0;
    auto alloc = [&](size_t bytes) -> void* {
        void* p = ws + off;
        off = (off + bytes + 255) & ~size_t(255);
        return p;
    };
    int*   gcnt    = (int*)alloc(256 * 4);
    int*   gptr    = (int*)alloc(257 * 4);
    int*   gcur    = (int*)alloc(256 * 4);
    int*   rp4     = (int*)alloc((size_t)(M + 1) * 4);
    float* dis     = (float*)alloc((size_t)N * 4);
    int*   gend    = (int*)alloc(256 * 4);
    int*   tmp     = (int*)alloc((size_t)E * 4);
    int*   csr     = (int*)alloc(((size_t)E + (size_t)G1 * GSLACK + 64) * 4);  // padded
    float* hs_a    = (float*)alloc((size_t)(N + 1) * 32 * 4);   // +1: zero sentinel row
    float* hs_b    = (float*)alloc((size_t)(N + 1) * 32 * 4);
    float* Mn      = (float*)alloc(32 * 32 * 10 * 4);
    float* Rw      = (float*)alloc(32 * 32 * 10 * 4);
    float* C0      = (float*)alloc(320 * 4);

    hipMemsetAsync(gcnt, 0, 256 * 4, stream);
    k_chist<<<2048, 256, 0, stream>>>(dst, E, gcnt, G1);      // R18: was 256 blocks (9% occ)
    k_cscan<<<1, 256, 0, stream>>>(gcnt, gptr, gcur, G1, E);
    k_cscatter<<<2048, 256, 0, stream>>>(src, dst, E, gcur, tmp, G1);  // R18: was 256
    k_build<<<G1, 256, 0, stream>>>(tmp, gptr, rp4, csr, dis, gend, N, M);
    k_mnorm<<<(32 * 32 * 10 + 255) / 256, 256, 0, stream>>>(W2, Mn, Rw, C0);

    const int gb0 = (N + 7) / 8;              // 12500 blocks, 8 nodes each (R13 grid)
    k_x0<<<gb0, 256, 0, stream>>>(x, W1, b1, b2, C0, dis, hs_a, out, N);

    const int gb = (N + 15) / 16;             // R18: 6250 blocks, 16 nodes each
    float* hin = hs_a; float* hout = hs_b;
    for (int j = 1; j <= 31; ++j) {
        int israw = (j == 1 || j == 16) ? 1 : 0;
        k_gcn<<<gb, 256, 0, stream>>>((const float4*)hin, (float4*)hout, dis, rp4,
                                      csr, gend,
                                      Wc + (size_t)(j - 1) * 1024,
                                      bc + (size_t)(j - 1) * 32,
                                      Mn + (size_t)j * 320,
                                      Rw + (size_t)j * 320,
                                      out, N, israw);
        float* t = hin; hin = hout; hout = t;
    }
}

// Round 7
// 1870.923 us; speedup vs baseline: 1.2175x; 1.2175x over previous
//
#include <hip/hip_runtime.h>

// SDGCN32: 31-layer GCN, N=100k, E=3.2M, F=32.
//  - hs = dis*h carried FP32, row-major [n][32] (fp16 carrier fails 31-layer error amp)
//  - CSR per (dst, src-bucket), NB=4 (R7 optimum); padded to x4 per segment (R17),
//    pad slots -> sentinel row N kept all-zero in hs (exact no-op adds).
//  - R19 post-mortem (both R18 edits falsified by counters):
//    (a) k_cscatter at 2048 blocks: WRITE_SIZE 15->69MB (per-(block,bin) reservation
//        shrank 64->8 ints => partial-line write amp; R10's k_fill disease). 63->87us.
//        LESSON: scatter TLP must come from THREADS/BLOCK, not block count.
//    (b) k_gcn 2-half split: ~56 -> ~68us/layer (doubled per-wave fixed overhead vs
//        shorter chain). Reverted to R17 8-node x 8-quad form. Do not revisit either.
//  - R20: k_cscatter/k_chist at 256 blocks x 1024 threads (16 waves/CU, reservation
//    clustering preserved). k_gcn/k_x0/k_build = R17 verbatim.
//  - R17 k_gcn: remainder-free padded CSR, ONE int4 index load per 4 edges,
//    prefetched one iteration ahead; group-last nodes' bucket-3 end = gend[g]
//    (NOT rp4[rbase+4] -> next group's base across unused slack -> garbage).
//  - k_x0 (R15): 8 nodes/block; n0==x0 identity; transpose epilogue. (R14's 64-node
//    serial-group variant regressed: barriers killed TLP; do not revisit.)
//  - out accumulated online: out += mynorm(x_j)@Mn_j (+ raw x_j@Rw_j, j in {0,1,16})

#define NB 4        // src buckets
#define BSHIFT 15   // bucket = src >> 15 (32768 nodes = 4 MiB fp32 chunk)
#define CSH 9       // coarse bin = dst >> 9 (512 nodes)
#define GSLACK 6152 // per-group csr padding slack: 2048 bins * 3 + alignment

__device__ __forceinline__ float shflx(float v, int m) { return __shfl_xor(v, m, 64); }

// ---------- pass A1: coarse histogram (R20: 1024 thr, 256 blocks) ----------
__global__ __launch_bounds__(1024) void k_chist(const int* __restrict__ dst, int E,
                                                int* __restrict__ gcnt, int G1) {
    __shared__ int lh[256];
    if (threadIdx.x < 256) lh[threadIdx.x] = 0;
    __syncthreads();
    int chunk = (E + gridDim.x - 1) / gridDim.x;
    int s0 = blockIdx.x * chunk, s1 = min(E, s0 + chunk);
    for (int e = s0 + threadIdx.x; e < s1; e += 1024)
        atomicAdd(&lh[dst[e] >> CSH], 1);
    __syncthreads();
    if (threadIdx.x < G1 && lh[threadIdx.x])
        atomicAdd(&gcnt[threadIdx.x], lh[threadIdx.x]);
}

// ---------- pass A2: scan coarse bins (G1 <= 256) ----------
__global__ void k_cscan(const int* __restrict__ gcnt, int* __restrict__ gptr,
                        int* __restrict__ gcur, int G1, int E) {
    __shared__ int s[256];
    int t = threadIdx.x;
    int v = (t < G1) ? gcnt[t] : 0;
    s[t] = v;
    __syncthreads();
    for (int off = 1; off < 256; off <<= 1) {
        int tv = (t >= off) ? s[t - off] : 0;
        __syncthreads();
        s[t] += tv;
        __syncthreads();
    }
    if (t < G1) { int ex = s[t] - v; gptr[t] = ex; gcur[t] = ex; }
    if (t == 0) gptr[G1] = E;
}

// ---------- pass A3: reservation scatter (R20: 1024 thr, 256 blocks) ----------
// Block count MUST stay ~256: per-(block,bin) reservation size = chunk/G1 ~ 64 ints
// = full cache lines. More blocks => fragmented reservations => write amp (R19).
__global__ __launch_bounds__(1024) void k_cscatter(const int* __restrict__ src,
                                                   const int* __restrict__ dst, int E,
                                                   int* __restrict__ gcur,
                                                   int* __restrict__ tmp, int G1) {
    __shared__ int lh[256], lc[256];
    if (threadIdx.x < 256) lh[threadIdx.x] = 0;
    __syncthreads();
    int chunk = (E + gridDim.x - 1) / gridDim.x;
    int s0 = blockIdx.x * chunk, s1 = min(E, s0 + chunk);
    for (int e = s0 + threadIdx.x; e < s1; e += 1024)
        atomicAdd(&lh[dst[e] >> CSH], 1);
    __syncthreads();
    if (threadIdx.x < G1) {
        int c = lh[threadIdx.x];
        lc[threadIdx.x] = c ? atomicAdd(&gcur[threadIdx.x], c) : 0;
    }
    __syncthreads();
    for (int e = s0 + threadIdx.x; e < s1; e += 1024) {
        int d = dst[e];
        int pos = atomicAdd(&lc[d >> CSH], 1);
        tmp[pos] = src[e] | ((d & ((1 << CSH) - 1)) << 17);
    }
}

// ---------- pass B: per coarse group -> PADDED fine CSR (rp4, csr, dis, gend) ----------
__global__ __launch_bounds__(256) void k_build(const int* __restrict__ tmp,
                                               const int* __restrict__ gptr,
                                               int* __restrict__ rp4,
                                               int* __restrict__ csr,
                                               float* __restrict__ dis,
                                               int* __restrict__ gend,
                                               int N, int M) {
    __shared__ int h[2048];     // fine bins: 512 nodes x NB
    __shared__ int c[2048];     // absolute scatter cursors
    __shared__ int s[256];
    int g = blockIdx.x;
    int gb = gptr[g], ge = gptr[g + 1];
    int gbP = ((gb + 3) & ~3) + g * GSLACK;
    int t = threadIdx.x;
#pragma unroll
    for (int k = 0; k < 8; ++k) h[t * 8 + k] = 0;
    __syncthreads();
    for (int e = gb + t; e < ge; e += 256) {
        int w = tmp[e];
        int srcv = w & 0x1FFFF, ldst = w >> 17;
        atomicAdd(&h[ldst * NB + (srcv >> BSHIFT)], 1);
    }
    __syncthreads();
    int base8 = t * 8;
    int loc[8], sumP = 0;
#pragma unroll
    for (int k = 0; k < 8; ++k) { loc[k] = h[base8 + k]; sumP += (loc[k] + 3) & ~3; }
    s[t] = sumP;
    __syncthreads();
    for (int off = 1; off < 256; off <<= 1) {
        int tv = (t >= off) ? s[t - off] : 0;
        __syncthreads();
        s[t] += tv;
        __syncthreads();
    }
    int runP = s[t] - sumP;
    int rowbase = g * 2048;
#pragma unroll
    for (int k = 0; k < 8; ++k) {
        int i = base8 + k;
        int abs0 = gbP + runP;
        c[i] = abs0;
        int ig = rowbase + i;
        if (ig <= M) rp4[ig] = abs0;
        int lp = (loc[k] + 3) & ~3;
        for (int j = loc[k]; j < lp; ++j) csr[abs0 + j] = N;   // sentinel pads
        runP += lp;
    }
    __syncthreads();
    for (int e = gb + t; e < ge; e += 256) {
        int w = tmp[e];
        int srcv = w & 0x1FFFF, ldst = w >> 17;
        int pos = atomicAdd(&c[ldst * NB + (srcv >> BSHIFT)], 1);
        csr[pos] = srcv;
    }
    // degrees -> dis (actual counts, not padded)
    int nodebase = g << CSH;
    for (int ln = t; ln < (1 << CSH); ln += 256) {
        int n = nodebase + ln;
        if (n < N) {
            int d = h[ln * NB] + h[ln * NB + 1] + h[ln * NB + 2] + h[ln * NB + 3];
            dis[n] = rsqrtf((float)d + 1.0f);
        }
    }
    if (t == 0) gend[g] = gbP + s[255];                        // true padded end
    if (g == gridDim.x - 1 && t == 0) rp4[M] = gbP + s[255];   // padded end marker
}

// ---------- coefficients, layout [j][o][c]; C0 = Mn[j=0] + Rw[j=0] (n0==x0 identity) ----------
__global__ void k_mnorm(const float* __restrict__ W2, float* __restrict__ Mn,
                        float* __restrict__ Rw, float* __restrict__ C0) {
    int idx = blockIdx.x * blockDim.x + threadIdx.x;
    if (idx >= 32 * 32 * 10) return;
    int c = idx % 32, o = (idx / 32) % 10, j = idx / 320;
    float v = 0.f;
    if (j >= 2 && j != 16) v += W2[(32 * j + c) * 10 + o];
    if (j <= 29 && j != 14) v -= W2[(32 * (j + 2) + c) * 10 + o];
    Mn[idx] = v;
    float rw = (j == 0 || j == 1 || j == 16) ? W2[(32 * j + c) * 10 + o] : 0.f;
    Rw[idx] = rw;
    if (j == 0) C0[idx] = v + rw;    // idx = o*32+c for j==0
}

// ---------- layer 0 (R15): R13 structure + transpose epilogue ----------
__global__ __launch_bounds__(256) void k_x0(
    const float* __restrict__ x, const float* __restrict__ W1, const float* __restrict__ b1,
    const float* __restrict__ b2, const float* __restrict__ C0,
    const float* __restrict__ dis, float* __restrict__ hs, float* __restrict__ out, int N)
{
    __shared__ float Wt[32 * 68];      // W1 transposed [c][k], pad 68 (bank spread)
    __shared__ float xs[8 * 64];       // 8 staged x rows
    __shared__ float bs[32];
    __shared__ float Cs[10 * 36];      // combined j=0 coeffs [o][c], pad 36
    __shared__ float xmat[8 * 36];     // x0 transposed [node][c], pad 36
    int t = threadIdx.x;
    for (int i = t; i < 2048; i += 256) {
        int k = i >> 5, cc = i & 31;
        Wt[cc * 68 + k] = W1[i];
    }
    for (int i = t; i < 320; i += 256) {
        int o = i >> 5, cc = i & 31;
        Cs[o * 36 + cc] = C0[i];
    }
    if (t < 32) bs[t] = b1[t];
    // maintain all-zero sentinel row N of hs (gathered by padded csr slots)
    if (blockIdx.x == 0 && t < 32) hs[(size_t)N * 32 + t] = 0.f;
    int base = blockIdx.x * 8;
    {
        int nf2 = (min(N - base, 8)) * 32;               // float2 count
        const float2* x2 = (const float2*)(x + (size_t)base * 64);
        float2* xs2 = (float2*)xs;
        for (int i = t; i < nf2; i += 256) xs2[i] = x2[i];
    }
    __syncthreads();

    int node8 = t >> 5, c = t & 31;
    int n = base + node8;
    bool nvalid = (n < N);

    // 64-dot: xs broadcast (same addr per half) + Wt float4 (4-way conflict, 1.58x)
    const float4* xs4 = (const float4*)(xs + node8 * 64);
    const float4* Wt4 = (const float4*)(Wt + c * 68);
    float acc = bs[c];
#pragma unroll
    for (int k4 = 0; k4 < 16; ++k4) {
        float4 xv = xs4[k4];
        float4 wv = Wt4[k4];
        acc += xv.x * wv.x + xv.y * wv.y + xv.z * wv.z + xv.w * wv.w;
    }
    acc = fmaxf(acc, 0.f);

    // mynorm over this node's 32 channels (butterfly stays within 32-lane half)
    float mn = acc, mx = acc;
#pragma unroll
    for (int m = 1; m <= 16; m <<= 1) { mn = fminf(mn, shflx(mn, m)); mx = fmaxf(mx, shflx(mx, m)); }
    float x0 = 2.f * (acc - mn) / (mx - mn + 1e-8f) - 1.f;
    if (nvalid) {
        float dn = dis[n];
        hs[(size_t)n * 32 + c] = dn * x0;                // 2x128B coalesced per wave
        xmat[node8 * 36 + c] = x0;                       // conflict-free (stride 36)
    }
    // n0 = mynorm(x0) == x0 to ~1e-8 (x0 already spans [-1,1]); butterfly #2 deleted.
    __syncthreads();

    // out init via transpose: 80 threads, one (node,o) each; 8x float4 LDS dot.
    if (t < 80) {
        int n8 = t / 10, o = t - n8 * 10;
        int no = base + n8;
        if (no < N) {
            const float4* xr = (const float4*)(xmat + n8 * 36);
            const float4* cr = (const float4*)(Cs + o * 36);
            float a = 0.f;
#pragma unroll
            for (int k = 0; k < 8; ++k) {
                float4 xv = xr[k];
                float4 cv = cr[k];
                a += xv.x * cv.x + xv.y * cv.y + xv.z * cv.z + xv.w * cv.w;
            }
            out[(size_t)no * 10 + o] = b2[o] + a;        // 320B contiguous per block
        }
    }
}

// ---------- GCN layer (R17 verbatim): prefetched int4 indices, padded CSR ----------
__global__ __launch_bounds__(256) void k_gcn(
    const float4* __restrict__ hs_in, float4* __restrict__ hs_out,
    const float* __restrict__ dis, const int* __restrict__ rp4,
    const int* __restrict__ csr, const int* __restrict__ gend,
    const float* __restrict__ W, const float* __restrict__ b,
    const float* __restrict__ Mn, const float* __restrict__ Rw,
    float* __restrict__ out, int N, int israw)
{
    __shared__ float Ws[1024];   // W [k][c]
    __shared__ float bs[32];
    __shared__ float Ms[320];    // Mn_j [o][c]
    __shared__ float Rs[320];    // Rw_j [o][c]
    for (int i = threadIdx.x; i < 1024; i += 256) Ws[i] = W[i];
    for (int i = threadIdx.x; i < 320; i += 256) { Ms[i] = Mn[i]; Rs[i] = Rw[i]; }
    if (threadIdx.x < 32) bs[threadIdx.x] = b[threadIdx.x];
    // keep sentinel row N of hs_out all-zero for the NEXT layer's gathers
    if (blockIdx.x == 0 && threadIdx.x < 8)
        hs_out[(size_t)N * 8 + threadIdx.x] = make_float4(0.f, 0.f, 0.f, 0.f);
    __syncthreads();

    int lane = threadIdx.x & 63;
    int q = lane & 7;            // channel quad c = 4q..4q+3
    int i8 = lane >> 3;          // node-sub 0..7
    int wave = threadIdx.x >> 6;
    int n = blockIdx.x * 32 + wave * 8 + i8;
    bool valid = (n < N);
    int nn = valid ? n : (N - 1);       // clamp: extra harmless loads only

    // self-loop term; lanes (i,0..7) -> 8 consecutive 128B rows = 1KB coalesced
    float4 acc = hs_in[(size_t)nn * 8 + q];

    int rbase = nn * NB;
    int rs = rp4[rbase];
    // bucket-3 terminator: group-last nodes must use the group's true padded end
    int e3 = ((nn & ((1 << CSH) - 1)) == ((1 << CSH) - 1)) ? gend[nn >> CSH]
                                                          : rp4[rbase + 4];
    const int4* csr4 = (const int4*)csr;
    int4 idx = csr4[rs >> 2];            // prefetch first quad (segments 16B-aligned)
    for (int p = 0; p < NB; ++p) {
        int re = (p == NB - 1) ? e3 : rp4[rbase + p + 1];   // segment continuity
        for (int e = rs; e < re; e += 4) {
            int s0 = idx.x, s1 = idx.y, s2 = idx.z, s3 = idx.w;
            idx = csr4[(e + 4) >> 2];   // prefetch next quad (tail overrun lands in
                                        // allocated slack; value then unused)
            float4 v0 = hs_in[(size_t)(s0 * 8 + q)];
            float4 v1 = hs_in[(size_t)(s1 * 8 + q)];
            float4 v2 = hs_in[(size_t)(s2 * 8 + q)];
            float4 v3 = hs_in[(size_t)(s3 * 8 + q)];
            acc.x += v0.x; acc.y += v0.y; acc.z += v0.z; acc.w += v0.w;
            acc.x += v1.x; acc.y += v1.y; acc.z += v1.z; acc.w += v1.w;
            acc.x += v2.x; acc.y += v2.y; acc.z += v2.z; acc.w += v2.w;
            acc.x += v3.x; acc.y += v3.y; acc.z += v3.z; acc.w += v3.w;
        }
        rs = re;
        __syncthreads();         // bucket phase alignment (uniform: all threads loop NB times)
    }

    float dn = dis[nn];
    float4 g = make_float4(dn * acc.x, dn * acc.y, dn * acc.z, dn * acc.w);

    // GEMM: xn[quad q of node i] = b + sum_k g_i[k] * W[k][4q..4q+3]
    const float4* W4 = (const float4*)Ws;
    float4 bb = ((const float4*)bs)[q];
    float4 xn = bb;
    int ibase = lane & 0x38;     // i8<<3
#pragma unroll
    for (int kp = 0; kp < 8; ++kp) {
        int sl = ibase | kp;     // lane holding quad kp of node i
        float gx = __shfl(g.x, sl, 64);
        float gy = __shfl(g.y, sl, 64);
        float gz = __shfl(g.z, sl, 64);
        float gw = __shfl(g.w, sl, 64);
        float4 w0 = W4[(kp * 4 + 0) * 8 + q];
        float4 w1 = W4[(kp * 4 + 1) * 8 + q];
        float4 w2 = W4[(kp * 4 + 2) * 8 + q];
        float4 w3 = W4[(kp * 4 + 3) * 8 + q];
        xn.x += gx * w0.x + gy * w1.x + gz * w2.x + gw * w3.x;
        xn.y += gx * w0.y + gy * w1.y + gz * w2.y + gw * w3.y;
        xn.z += gx * w0.z + gy * w1.z + gz * w2.z + gw * w3.z;
        xn.w += gx * w0.w + gy * w1.w + gz * w2.w + gw * w3.w;
    }

    if (valid)
        hs_out[(size_t)n * 8 + q] = make_float4(dn * xn.x, dn * xn.y, dn * xn.z, dn * xn.w);

    // mynorm over node's 32 channels: local 4, then butterfly over q bits (1,2,4)
    float mn = fminf(fminf(xn.x, xn.y), fminf(xn.z, xn.w));
    float mx = fmaxf(fmaxf(xn.x, xn.y), fmaxf(xn.z, xn.w));
#pragma unroll
    for (int m = 1; m <= 4; m <<= 1) { mn = fminf(mn, shflx(mn, m)); mx = fmaxf(mx, shflx(mx, m)); }
    float sc = 2.f / (mx - mn + 1e-8f);
    float4 nr = make_float4((xn.x - mn) * sc - 1.f, (xn.y - mn) * sc - 1.f,
                            (xn.z - mn) * sc - 1.f, (xn.w - mn) * sc - 1.f);

    // out accum: t[o] = nr . Mn[o][:] (+ xn . Rw[o][:]); butterfly within q bits
    const float4* M4 = (const float4*)Ms;
    const float4* R4 = (const float4*)Rs;
    float outA = 0.f, outB = 0.f;
#pragma unroll
    for (int o = 0; o < 10; ++o) {
        float4 m4 = M4[o * 8 + q];
        float t = nr.x * m4.x + nr.y * m4.y + nr.z * m4.z + nr.w * m4.w;
        if (israw) {
            float4 r4 = R4[o * 8 + q];
            t += xn.x * r4.x + xn.y * r4.y + xn.z * r4.z + xn.w * r4.w;
        }
        t += shflx(t, 1); t += shflx(t, 2); t += shflx(t, 4);
        if (o == q) outA = t;
        if (o == 8 + q) outB = t;
    }
    if (valid) {
        out[n * 10 + q] += outA;
        if (q < 2) out[n * 10 + 8 + q] += outB;
    }
}

extern "C" void kernel_launch(void* const* d_in, const int* in_sizes, int n_in,
                              void* d_out, int out_size, void* d_ws, size_t ws_size,
                              hipStream_t stream)
{
    const float* x  = (const float*)d_in[0];
    const int*   ei = (const int*)d_in[1];
    const float* W1 = (const float*)d_in[2];
    const float* b1 = (const float*)d_in[3];
    const float* Wc = (const float*)d_in[4];
    const float* bc = (const float*)d_in[5];
    const float* W2 = (const float*)d_in[6];
    const float* b2 = (const float*)d_in[7];
    float* out = (float*)d_out;

    const int N = in_sizes[0] / 64;
    const int E = in_sizes[1] / 2;
    const int M = N * NB;                     // (node,bucket) rows
    const int G1 = (N + (1 << CSH) - 1) >> CSH;   // 196 coarse bins (<=256)
    const int* src = ei;
    const int* dst = ei + E;

    char* ws = (char*)d_ws;
    size_t off = 0;
    auto alloc = [&](size_t bytes) -> void* {
        void* p = ws + off;
        off = (off + bytes + 255) & ~size_t(255);
        return p;
    };
    int*   gcnt    = (int*)alloc(256 * 4);
    int*   gptr    = (int*)alloc(257 * 4);
    int*   gcur    = (int*)alloc(256 * 4);
    int*   rp4     = (int*)alloc((size_t)(M + 1) * 4);
    float* dis     = (float*)alloc((size_t)N * 4);
    int*   gend    = (int*)alloc(256 * 4);
    int*   tmp     = (int*)alloc((size_t)E * 4);
    int*   csr     = (int*)alloc(((size_t)E + (size_t)G1 * GSLACK + 64) * 4);  // padded
    float* hs_a    = (float*)alloc((size_t)(N + 1) * 32 * 4);   // +1: zero sentinel row
    float* hs_b    = (float*)alloc((size_t)(N + 1) * 32 * 4);
    float* Mn      = (float*)alloc(32 * 32 * 10 * 4);
    float* Rw      = (float*)alloc(32 * 32 * 10 * 4);
    float* C0      = (float*)alloc(320 * 4);

    hipMemsetAsync(gcnt, 0, 256 * 4, stream);
    k_chist<<<256, 1024, 0, stream>>>(dst, E, gcnt, G1);       // R20: 16 waves/CU
    k_cscan<<<1, 256, 0, stream>>>(gcnt, gptr, gcur, G1, E);
    k_cscatter<<<256, 1024, 0, stream>>>(src, dst, E, gcur, tmp, G1);  // R20
    k_build<<<G1, 256, 0, stream>>>(tmp, gptr, rp4, csr, dis, gend, N, M);
    k_mnorm<<<(32 * 32 * 10 + 255) / 256, 256, 0, stream>>>(W2, Mn, Rw, C0);

    const int gb0 = (N + 7) / 8;              // 12500 blocks, 8 nodes each (R13 grid)
    k_x0<<<gb0, 256, 0, stream>>>(x, W1, b1, b2, C0, dis, hs_a, out, N);

    const int gb = (N + 31) / 32;             // 3125 blocks, 32 nodes each (R17 grid)
    float* hin = hs_a; float* hout = hs_b;
    for (int j = 1; j <= 31; ++j) {
        int israw = (j == 1 || j == 16) ? 1 : 0;
        k_gcn<<<gb, 256, 0, stream>>>((const float4*)hin, (float4*)hout, dis, rp4,
                                      csr, gend,
                                      Wc + (size_t)(j - 1) * 1024,
                                      bc + (size_t)(j - 1) * 32,
                                      Mn + (size_t)j * 320,
                                      Rw + (size_t)j * 320,
                                      out, N, israw);
        float* t = hin; hin = hout; hout = t;
    }
}